// Round 15
// baseline (60.710 us; speedup 1.0000x reference)
//
#include <hip/hip_runtime.h>
#include <hip/hip_bf16.h>

#define LQ 4096
#define DD 64
#define NB 4
#define NTOT ((size_t)NB * LQ * DD)
#define NROW ((size_t)NB * LQ)

typedef __attribute__((ext_vector_type(4))) float f32x4;
typedef __attribute__((ext_vector_type(8))) short short8;
typedef __attribute__((ext_vector_type(4))) short short4v;
typedef __attribute__((ext_vector_type(2))) unsigned int uint2v;
typedef __attribute__((ext_vector_type(4))) unsigned short ushort4v;

static __device__ __forceinline__ unsigned short f2bf(float x) {
  __hip_bfloat16 h = __float2bfloat16(x);
  return __builtin_bit_cast(unsigned short, h);
}
static __device__ __forceinline__ float bf2f(unsigned short u) {
  unsigned int v = ((unsigned int)u) << 16;
  return __builtin_bit_cast(float, v);
}
static __device__ __forceinline__ float ex2(float x) { return __builtin_amdgcn_exp2f(x); }

static __device__ __forceinline__ f32x4 mfma16(short4v a, short4v b, f32x4 c) {
#if __has_builtin(__builtin_amdgcn_mfma_f32_16x16x16bf16_1k)
  return __builtin_amdgcn_mfma_f32_16x16x16bf16_1k(a, b, c, 0, 0, 0);
#else
  asm volatile("v_mfma_f32_16x16x16_bf16 %0, %1, %2, %0"
               : "+v"(c) : "v"(a), "v"(b));
  return c;
#endif
}

// async global->LDS, 16B per lane, dest = ldsbase + lane*16
static __device__ __forceinline__ void gl_lds16(const unsigned short* g, unsigned short* l) {
  __builtin_amdgcn_global_load_lds(
      (const __attribute__((address_space(1))) unsigned int*)g,
      (__attribute__((address_space(3))) unsigned int*)l, 16, 0, 0);
}

// score scale folded into log2 domain: s2 = T * (0.125 * log2(e))
#define C1 0.18033688011112042f

// ---------------------------------------------------------------------------
// prep: pure cast Q,K,V -> bf16 (layouts unchanged, [b][i][d])
// ---------------------------------------------------------------------------
__global__ __launch_bounds__(256) void prep_kernel(
    const float* __restrict__ q, const float* __restrict__ k,
    const float* __restrict__ v,
    unsigned short* __restrict__ Qb, unsigned short* __restrict__ Kb,
    unsigned short* __restrict__ Vb)
{
  const int arr = blockIdx.x >> 9;
  const size_t off = (((size_t)(blockIdx.x & 511)) * 256 + threadIdx.x) * 8;
  const float* s = arr == 0 ? q : arr == 1 ? k : v;
  unsigned short* d = arr == 0 ? Qb : arr == 1 ? Kb : Vb;
  const f32x4 x0 = *(const f32x4*)(s + off);
  const f32x4 x1 = *(const f32x4*)(s + off + 4);
  ushort4v o0 = { f2bf(x0[0]), f2bf(x0[1]), f2bf(x0[2]), f2bf(x0[3]) };
  ushort4v o1 = { f2bf(x1[0]), f2bf(x1[1]), f2bf(x1[2]), f2bf(x1[3]) };
  *(ushort4v*)(d + off) = o0;
  *(ushort4v*)(d + off + 4) = o1;
}

// ---------------------------------------------------------------------------
// stats (round-11 exact): part_ls[jc][b*LQ+i] = sum_{j in chunk} exp2(T*C1)
// grid: NB*16*8 = 512 blocks of 256. Block: i-tile 256, j-chunk 512.
// ---------------------------------------------------------------------------
__global__ __launch_bounds__(256, 2) void stats_kernel(
    const unsigned short* __restrict__ Qb, const unsigned short* __restrict__ Kb,
    float* __restrict__ part_ls)
{
  __shared__ __align__(16) unsigned short stK[3][2048];
  const int bx = blockIdx.x;
  const int jc = bx & 7, it = (bx >> 3) & 15, b = bx >> 7;
  const int tid = threadIdx.x, w = tid >> 6, lane = tid & 63;
  const int l15 = lane & 15, g = lane >> 4;
  const int i0 = it * 256 + w * 64;
  const int jbase = jc * 512;
  const unsigned short* Kbase = Kb + (size_t)b * LQ * DD;

  short8 aq[4][2];
#pragma unroll
  for (int is = 0; is < 4; ++is)
#pragma unroll
    for (int kh = 0; kh < 2; ++kh)
      aq[is][kh] = *(const short8*)(Qb + ((size_t)b * LQ + i0 + is * 16 + l15) * DD + kh * 32 + g * 8);

  float ls[4][4];
#pragma unroll
  for (int is = 0; is < 4; ++is)
#pragma unroll
    for (int qq = 0; qq < 4; ++qq) ls[is][qq] = 0.f;

  const int srow = w * 8 + (lane >> 3);
  const int scol = ((lane & 7) ^ (lane >> 3)) << 3;

  gl_lds16(Kbase + (size_t)(jbase + srow) * DD + scol, &stK[0][w * 512]);
  gl_lds16(Kbase + (size_t)(jbase + 32 + srow) * DD + scol, &stK[1][w * 512]);
  asm volatile("s_waitcnt vmcnt(1)" ::: "memory");
  __builtin_amdgcn_s_barrier();

  for (int itr = 0; itr < 16; ++itr) {
    const int cur = itr % 3;
    const int tn = (itr + 2 < 16) ? itr + 2 : 15;
    gl_lds16(Kbase + (size_t)(jbase + tn * 32 + srow) * DD + scol, &stK[(itr + 2) % 3][w * 512]);

    short8 kf[2][2];
#pragma unroll
    for (int jsub = 0; jsub < 2; ++jsub)
#pragma unroll
      for (int kh = 0; kh < 2; ++kh) {
        const int row = jsub * 16 + l15;
        kf[jsub][kh] = *(const short8*)(&stK[cur][row * 64 + (((kh * 4 + g) ^ (l15 & 7)) << 3)]);
      }
#pragma unroll
    for (int is = 0; is < 4; ++is)
#pragma unroll
      for (int jsub = 0; jsub < 2; ++jsub) {
        f32x4 tt = __builtin_amdgcn_mfma_f32_16x16x32_bf16(
            aq[is][0], kf[jsub][0], (f32x4){0.f, 0.f, 0.f, 0.f}, 0, 0, 0);
        tt = __builtin_amdgcn_mfma_f32_16x16x32_bf16(aq[is][1], kf[jsub][1], tt, 0, 0, 0);
#pragma unroll
        for (int qq = 0; qq < 4; ++qq) ls[is][qq] += ex2(tt[qq] * C1);
      }
    asm volatile("s_waitcnt vmcnt(1)" ::: "memory");
    __builtin_amdgcn_s_barrier();
  }
#pragma unroll
  for (int mask = 1; mask <= 8; mask <<= 1)
#pragma unroll
    for (int is = 0; is < 4; ++is)
#pragma unroll
      for (int qq = 0; qq < 4; ++qq) ls[is][qq] += __shfl_xor(ls[is][qq], mask, 64);
  if (l15 == 0) {
#pragma unroll
    for (int is = 0; is < 4; ++is)
#pragma unroll
      for (int qq = 0; qq < 4; ++qq)
        part_ls[(size_t)jc * NROW + b * LQ + i0 + is * 16 + g * 4 + qq] = ls[is][qq];
  }
}

// ---------------------------------------------------------------------------
// combine: Vs[r][d] = Vb[r][d] / l_r ,  l_r = sum_{jc<8} part_ls[jc][r]
// ---------------------------------------------------------------------------
__global__ __launch_bounds__(256) void combine_kernel(
    const float* __restrict__ part_ls, const unsigned short* __restrict__ Vb,
    unsigned short* __restrict__ Vs)
{
  const size_t base = ((size_t)blockIdx.x * 256 + threadIdx.x) * 8;
  const int r = (int)(base >> 6);
  float l = 0.f;
#pragma unroll
  for (int jc = 0; jc < 8; ++jc) l += part_ls[(size_t)jc * NROW + r];
  const float s = 1.0f / l;
  const ushort4v a = *(const ushort4v*)(Vb + base);
  const ushort4v c = *(const ushort4v*)(Vb + base + 4);
  ushort4v oa = { f2bf(bf2f(a[0]) * s), f2bf(bf2f(a[1]) * s),
                  f2bf(bf2f(a[2]) * s), f2bf(bf2f(a[3]) * s) };
  ushort4v oc = { f2bf(bf2f(c[0]) * s), f2bf(bf2f(c[1]) * s),
                  f2bf(bf2f(c[2]) * s), f2bf(bf2f(c[3]) * s) };
  *(ushort4v*)(Vs + base) = oa;
  *(ushort4v*)(Vs + base + 4) = oc;
}

// ---------------------------------------------------------------------------
// attn_out: out[j][d] = sum_i exp2(T[j,i]*C1) * Vs[i][d]   (fp32, no split)
// grid: NB*64 = 256 blocks of 1024 (16 waves = 4 waves/SIMD). Wave
// (p=w>>1, sub=w&1): j-half jt*64+sub*32 (2 js), i-range [p*512,+512) as
// 32 iters of 16 rows. PRIVATE DOUBLE-BUFFERED stage (2 x 4KB/wave,
// 128 KB total): prefetch 2 tiles ahead, counted vmcnt(4) at iter top
// (never 0 except last iter). Swapped QK keeps P in registers; PV via
// K=16 MFMAs with single-tr-read V frags. No block barriers in loop.
// ---------------------------------------------------------------------------
__global__ __launch_bounds__(1024, 4) void attn_out_kernel(
    const unsigned short* __restrict__ Qb, const unsigned short* __restrict__ Kb,
    const unsigned short* __restrict__ Vs, float* __restrict__ out)
{
  __shared__ __align__(16) unsigned short stage[16][2][2048]; // 128 KB [wave][buf][Q 1K|V 1K]

  const int bx = blockIdx.x;
  const int jt = bx & 63;
  const int b  = bx >> 6;
  const int tid = threadIdx.x, w = tid >> 6, lane = tid & 63;
  const int p = w >> 1, sub = w & 1;
  const int l15 = lane & 15, g = lane >> 4;
  const int j0 = jt * 64 + sub * 32;

  const unsigned short* Qbase = Qb + (size_t)b * LQ * DD;
  const unsigned short* Vbase = Vs + (size_t)b * LQ * DD;

  // K frags (B-operand of swapped QK): data K[j=l15][d=g*8+r] per kh-half
  short8 ka[2][2];
#pragma unroll
  for (int jsl = 0; jsl < 2; ++jsl)
#pragma unroll
    for (int kh = 0; kh < 2; ++kh)
      ka[jsl][kh] = *(const short8*)(Kb + ((size_t)b * LQ + j0 + jsl * 16 + l15) * DD + kh * 32 + g * 8);

  f32x4 acc[2][4];
#pragma unroll
  for (int jsl = 0; jsl < 2; ++jsl)
#pragma unroll
    for (int ds = 0; ds < 4; ++ds) acc[jsl][ds] = (f32x4){0.f, 0.f, 0.f, 0.f};

  const int ibase = p * 512;
  // staging source addressing (row-coalesced 1KB blocks)
  const int qrow = lane >> 3;                 // + 8*kk
  const int qcol = ((lane & 7) ^ (lane >> 3)) << 3;
  // V [ds][g][r][c] subtile layout: i = vgr, d = kk*32 + vdc
  const int vgr = ((lane & 31) >> 3) * 4 + ((lane >> 1) & 3);
  const int vdc = (lane >> 5) * 16 + (lane & 1) * 8;

  const unsigned sbyte = (unsigned)(size_t)&stage[w][0][0];

#define STAGE(BUF, I0) do { \
    _Pragma("unroll") \
    for (int kk = 0; kk < 2; ++kk) { \
      gl_lds16(Qbase + (size_t)((I0) + kk * 8 + qrow) * DD + qcol, &stage[w][BUF][kk * 512]); \
      gl_lds16(Vbase + (size_t)((I0) + vgr) * DD + kk * 32 + vdc, &stage[w][BUF][1024 + kk * 512]); \
    } \
  } while (0)

  STAGE(0, ibase);
  STAGE(1, ibase + 16);

  for (int itr = 0; itr < 32; ++itr) {
    const int cur = itr & 1;
    // tile itr (issued 2 iters ago) retired; next tile's 4 loads may fly
    if (itr < 31) asm volatile("s_waitcnt vmcnt(4)" ::: "memory");
    else          asm volatile("s_waitcnt vmcnt(0)" ::: "memory");

    // Q A-frags from swizzled LDS: data Q[i=l15][d=kh*32+g*8+r]
    short8 qf[2];
#pragma unroll
    for (int kh = 0; kh < 2; ++kh)
      qf[kh] = *(const short8*)(&stage[w][cur][l15 * 64 + (((kh * 4 + g) ^ (l15 & 7)) << 3)]);

    // V K=16 B-frags via tr-read (frag ds at +ds*512); ends lgkmcnt(0) =>
    // Q reads also landed in regs before the buffer is re-staged below.
    unsigned long long v0, v1, v2, v3;
    const unsigned av = sbyte + cur * 4096 + 2048 + g * 128 + l15 * 8;
    asm volatile(
        "ds_read_b64_tr_b16 %0, %4\n\t"
        "ds_read_b64_tr_b16 %1, %4 offset:512\n\t"
        "ds_read_b64_tr_b16 %2, %4 offset:1024\n\t"
        "ds_read_b64_tr_b16 %3, %4 offset:1536\n\t"
        "s_waitcnt lgkmcnt(0)"
        : "=&v"(v0), "=&v"(v1), "=&v"(v2), "=&v"(v3)
        : "v"(av) : "memory");
    short4v vf[4];
    vf[0] = __builtin_bit_cast(short4v, v0);
    vf[1] = __builtin_bit_cast(short4v, v1);
    vf[2] = __builtin_bit_cast(short4v, v2);
    vf[3] = __builtin_bit_cast(short4v, v3);

    // re-stage this buffer with tile itr+2 (reads above already in regs)
    if (itr + 2 < 32) STAGE(cur, ibase + (itr + 2) * 16);

    // per j-subtile: swapped QK -> P (j lane-local) -> pack -> K=16 PV
    __builtin_amdgcn_s_setprio(1);
#pragma unroll
    for (int jsl = 0; jsl < 2; ++jsl) {
      f32x4 tt = __builtin_amdgcn_mfma_f32_16x16x32_bf16(
          qf[0], ka[jsl][0], (f32x4){0.f, 0.f, 0.f, 0.f}, 0, 0, 0);
      tt = __builtin_amdgcn_mfma_f32_16x16x32_bf16(qf[1], ka[jsl][1], tt, 0, 0, 0);
      const unsigned a0 = __builtin_bit_cast(unsigned, ex2(tt[0] * C1)) + 0x8000u;
      const unsigned a1 = __builtin_bit_cast(unsigned, ex2(tt[1] * C1)) + 0x8000u;
      const unsigned a2 = __builtin_bit_cast(unsigned, ex2(tt[2] * C1)) + 0x8000u;
      const unsigned a3 = __builtin_bit_cast(unsigned, ex2(tt[3] * C1)) + 0x8000u;
      uint2v uu;
      uu[0] = __builtin_amdgcn_perm(a1, a0, 0x07060302u);
      uu[1] = __builtin_amdgcn_perm(a3, a2, 0x07060302u);
      const short4v pa = __builtin_bit_cast(short4v, uu);
      acc[jsl][0] = mfma16(pa, vf[0], acc[jsl][0]);
      acc[jsl][1] = mfma16(pa, vf[1], acc[jsl][1]);
      acc[jsl][2] = mfma16(pa, vf[2], acc[jsl][2]);
      acc[jsl][3] = mfma16(pa, vf[3], acc[jsl][3]);
    }
    __builtin_amdgcn_s_setprio(0);
  }
#undef STAGE

  // cross-wave i-reduce: all 16 waves dump acc (128 KB = stage reuse),
  // wave w sums + stores j-rows [w*4, w*4+4) over the 8 i-range copies.
  __syncthreads();
  float* red = (float*)&stage[0][0][0];   // 16 x 2048 floats = 128 KB
#pragma unroll
  for (int jsl = 0; jsl < 2; ++jsl)
#pragma unroll
    for (int ds = 0; ds < 4; ++ds)
#pragma unroll
      for (int qq = 0; qq < 4; ++qq)
        red[w * 2048 + (jsl * 16 + g * 4 + qq) * 64 + ds * 16 + l15] = acc[jsl][ds][qq];
  __syncthreads();
  {
    float* op = out + ((size_t)b * LQ + jt * 64) * DD;
#pragma unroll
    for (int rr = 0; rr < 4; ++rr) {
      const int r = w * 4 + rr;          // 0..63 within the j-tile
      const int sr = r >> 5, rl = r & 31;
      float s = 0.f;
#pragma unroll
      for (int pp = 0; pp < 8; ++pp)
        s += red[(pp * 2 + sr) * 2048 + rl * 64 + lane];
      op[r * 64 + lane] = s;
    }
  }
}

// ---------------------------------------------------------------------------
extern "C" void kernel_launch(void* const* d_in, const int* in_sizes, int n_in,
                              void* d_out, int out_size, void* d_ws, size_t ws_size,
                              hipStream_t stream) {
  const float* q = (const float*)d_in[0];
  const float* k = (const float*)d_in[1];
  const float* v = (const float*)d_in[2];

  unsigned short* Qb = (unsigned short*)d_ws;
  unsigned short* Kb = Qb + NTOT;
  unsigned short* Vb = Kb + NTOT;
  unsigned short* Vs = Vb + NTOT;
  float* part_ls = (float*)(Vs + NTOT);
  float* outp = (float*)d_out;

  prep_kernel<<<1536, 256, 0, stream>>>(q, k, v, Qb, Kb, Vb);
  stats_kernel<<<NB * 16 * 8, 256, 0, stream>>>(Qb, Kb, part_ls);
  combine_kernel<<<512, 256, 0, stream>>>(part_ls, Vb, Vs);
  attn_out_kernel<<<NB * 64, 1024, 0, stream>>>(Qb, Kb, Vs, outp);
}